// Round 1
// baseline (902.127 us; speedup 1.0000x reference)
//
#include <hip/hip_runtime.h>

// GATReduce: a = sum_d(a1[n,d] + a2[n,k,d]) -> leaky_relu -> softmax over k
//            out[n,d] = sum_k e[n,k] * ft[n,k,d]
// N=30000, DEG=32, D=128, fp32. Memory-bound: ~1.01 GB ideal traffic.
//
// Structure: ONE WAVE (64 lanes) per n. No LDS, no __syncthreads.
//  - half-wave h reads rows 2i+h as float4 (wave reads 1KB contiguous per iter)
//  - 32 row sums live in registers (rs[16] per lane, one half each)
//  - softmax entirely in-register: per-lane reduce over rs[] + one
//    cross-half __shfl_xor(...,32) for max and for sum
//  - phase 3 accumulates w*ft in float4, combines halves with 4 shuffles,
//    half 0 stores 512B coalesced.
// Removes the 3-barrier serialization of the previous version so the
// load stream never stalls; every wave is independent.

#define NN 30000
#define DEG 32
#define DD 128
#define NEG_SLOPE 0.01f

__global__ __launch_bounds__(256) void gat_reduce_kernel(
    const float* __restrict__ a1,
    const float* __restrict__ a2,
    const float* __restrict__ ft,
    float* __restrict__ out)
{
    const int wave = threadIdx.x >> 6;   // 0..3, each wave owns one n
    const int lane = threadIdx.x & 63;
    const int half = lane >> 5;          // 0 or 1
    const int l    = lane & 31;          // lane within half-wave
    const int n    = blockIdx.x * 4 + wave;   // 7500*4 = 30000 exact

    const float4* a2v = (const float4*)a2 + (size_t)n * (DEG * DD / 4);
    const float4* ftv = (const float4*)ft + (size_t)n * (DEG * DD / 4);
    const float2* a1v = (const float2*)a1 + (size_t)n * (DD / 2);

    // ---- a1[n,:] total: 64 lanes x float2 = 512B coalesced ----
    float2 av = a1v[lane];
    float c = av.x + av.y;
    #pragma unroll
    for (int m = 32; m >= 1; m >>= 1) c += __shfl_xor(c, m);

    // ---- Phase 1: 32 row sums of a2[n,k,:]; half h owns rows 2i+h ----
    // Wave reads 1KB contiguous per iteration; 16 independent iterations
    // fully unrolled -> deep memory-level parallelism, no barriers.
    float rs[16];
    #pragma unroll
    for (int i = 0; i < 16; ++i) {
        float4 v = a2v[(2 * i + half) * 32 + l];
        float s = v.x + v.y + v.z + v.w;
        #pragma unroll
        for (int m = 16; m >= 1; m >>= 1) s += __shfl_xor(s, m);  // stays in half
        rs[i] = s;   // every lane of this half holds the full row sum
    }

    // ---- Phase 2: leaky_relu + softmax over 32 neighbors, in-register ----
    float mx = -3.0e38f;
    #pragma unroll
    for (int i = 0; i < 16; ++i) {
        float a  = rs[i] + c;
        float lr = a > 0.0f ? a : NEG_SLOPE * a;
        rs[i] = lr;
        mx = fmaxf(mx, lr);
    }
    mx = fmaxf(mx, __shfl_xor(mx, 32));        // combine the two halves
    float ssum = 0.0f;
    #pragma unroll
    for (int i = 0; i < 16; ++i) {
        float p = __expf(rs[i] - mx);
        rs[i] = p;
        ssum += p;
    }
    ssum += __shfl_xor(ssum, 32);
    const float inv = 1.0f / ssum;

    // ---- Phase 3: out[n,:] = sum_k w_k * ft[n,k,:] ----
    float4 acc = make_float4(0.f, 0.f, 0.f, 0.f);
    #pragma unroll
    for (int i = 0; i < 16; ++i) {
        const float w = rs[i] * inv;
        float4 v = ftv[(2 * i + half) * 32 + l];
        acc.x += w * v.x;
        acc.y += w * v.y;
        acc.z += w * v.z;
        acc.w += w * v.w;
    }
    // fold odd-row half into even-row half
    acc.x += __shfl_xor(acc.x, 32);
    acc.y += __shfl_xor(acc.y, 32);
    acc.z += __shfl_xor(acc.z, 32);
    acc.w += __shfl_xor(acc.w, 32);
    if (half == 0) {
        ((float4*)out)[(size_t)n * 32 + l] = acc;   // 512B coalesced store
    }
}

extern "C" void kernel_launch(void* const* d_in, const int* in_sizes, int n_in,
                              void* d_out, int out_size, void* d_ws, size_t ws_size,
                              hipStream_t stream) {
    const float* a1 = (const float*)d_in[0];
    const float* a2 = (const float*)d_in[1];
    const float* ft = (const float*)d_in[2];
    float* out = (float*)d_out;
    gat_reduce_kernel<<<NN / 4, 256, 0, stream>>>(a1, a2, ft, out);
}